// Round 5
// baseline (15047.278 us; speedup 1.0000x reference)
//
#include <hip/hip_runtime.h>

#define NBATCH 128
#define DMODEL 512
#define FDIM 64
#define KIN 1024
#define NOUT 2048

typedef float v4f __attribute__((ext_vector_type(4)));
typedef float v2f __attribute__((ext_vector_type(2)));

struct Par {
  const float *input, *mask, *Wi, *bi, *gi, *bti;
  const float *Wd1, *bd1, *Wd2, *bd2;
  const float *Wc1, *bc1, *Wc2, *bc2, *gc, *btc;
  float *out;
  float *cs, *x, *h, *ct, *logits;
  int *pos, *ksel;
  unsigned int *bar;
};

__device__ __forceinline__ float gelu_f(float v) {
  float u = 0.7978845608028654f * (v + 0.044715f * v * v * v);
  return 0.5f * v * (1.0f + tanhf(u));
}
__device__ __forceinline__ float sigm_f(float v) { return 1.0f / (1.0f + expf(-v)); }

__device__ __forceinline__ float wred_sum(float v) {
#pragma unroll
  for (int o = 32; o > 0; o >>= 1) v += __shfl_xor(v, o, 64);
  return v;
}

__device__ __forceinline__ float4 nt_load4(const float* p) {
  v4f v = __builtin_nontemporal_load((const v4f*)p);
  float4 r;
  r.x = v.x; r.y = v.y; r.z = v.z; r.w = v.w;
  return r;
}
__device__ __forceinline__ void nt_store4(float* p, float4 q) {
  v4f v;
  v.x = q.x; v.y = q.y; v.z = q.z; v.w = q.w;
  __builtin_nontemporal_store(v, (v4f*)p);
}
__device__ __forceinline__ void nt_store2(float* p, float a, float b) {
  v2f v; v.x = a; v.y = b;
  __builtin_nontemporal_store(v, (v2f*)p);
}
__device__ __forceinline__ float nt_load1(const float* p) {
  return __builtin_nontemporal_load(p);
}

// monotonic-counter grid barrier (256 co-resident blocks)
__device__ __forceinline__ void gsync(unsigned int* bar, unsigned int* tgt) {
  __syncthreads();
  if (threadIdx.x == 0) {
    *tgt += gridDim.x;
    __hip_atomic_fetch_add(bar, 1u, __ATOMIC_ACQ_REL, __HIP_MEMORY_SCOPE_AGENT);
    while (__hip_atomic_load(bar, __ATOMIC_ACQUIRE, __HIP_MEMORY_SCOPE_AGENT) < *tgt)
      __builtin_amdgcn_s_sleep(1);
  }
  __syncthreads();
}

// ---- SEL: argmax + pos/logit shift + build x = [l_sel, r_sel]; stash x-row in LDS
__device__ void sel_phase(const Par& p, int i, int* sI, float* smem) {
  int n = blockIdx.x;
  int t = threadIdx.x, wave = t >> 6, lane = t & 63;
  int P = 63 - i;
  if (wave == 0) {
    float v = -3.0e38f;
    int idx = 1 << 20;
    if (lane < P) {
      v = p.logits[n * 64 + lane];
      float mk = p.mask[n * 64 + i + 1 + lane];
      if (!(mk > 0.0f)) v = -1.0e9f;
      idx = lane;
    }
#pragma unroll
    for (int o = 32; o > 0; o >>= 1) {
      float v2 = __shfl_xor(v, o, 64);
      int i2 = __shfl_xor(idx, o, 64);
      if (v2 > v || (v2 == v && i2 < idx)) { v = v2; idx = i2; }
    }
    if (lane == 0) {
      p.ksel[n] = idx;
      sI[0] = idx;
      sI[1] = p.pos[n * 64 + idx];
      sI[2] = p.pos[n * 64 + idx + 1];
    }
  }
  __syncthreads();
  int k = sI[0], slot_l = sI[1], slot_r = sI[2];
  if (wave == 1) {  // shift pos (wave-lockstep load-before-store)
    int j = lane;
    if (j >= k + 1 && j <= 62 - i) {
      int tmp = p.pos[n * 64 + j + 1];
      p.pos[n * 64 + j] = tmp;
    }
  } else if (wave == 2) {  // shift logits
    int j = lane;
    if (j >= k && j <= 61 - i) {
      float tmp = p.logits[n * 64 + j + 1];
      p.logits[n * 64 + j] = tmp;
    }
  }
  const float* csl = &p.cs[(size_t)(n * 64 + slot_l) * DMODEL];
  const float* csr = &p.cs[(size_t)(n * 64 + slot_r) * DMODEL];
  float* xg = &p.x[(size_t)n * KIN];
  float* sx = smem + 8192;  // LDS stash of this row's x (1024 floats)
  if (t < 128) {
    float4 v = *(const float4*)&csl[t * 4];
    nt_store4(&xg[t * 4], v);
    *(float4*)&sx[t * 4] = v;
  } else if (t < 256) {
    float4 v = *(const float4*)&csr[(t - 128) * 4];
    nt_store4(&xg[512 + (t - 128) * 4], v);
    *(float4*)&sx[512 + (t - 128) * 4] = v;
  }
}

// ---- GEMM1: h = gelu(x @ Wc1 + bc1); 8 Mtiles(16r) x 32 col-chunks(64c)
//      512 threads = 16 rows x 32 col-pairs; K in 2 LDS-staged halves; prefetch x2
__device__ void g1_phase(const Par& p, float* smem) {
  int b = blockIdx.x, t = threadIdx.x;
  int mt = b >> 5, nc = b & 31;  // b%8 == nc%8 -> XCD-pinned weight columns
  int rbase = mt * 16, cbase = nc * 64;
  float* xs = smem;  // [16][512]
  int row = t >> 5;
  int cg = cbase + (t & 31) * 2;
  int wcol = cg >> 1;
  const float2* W2 = (const float2*)p.Wc1;
  const int S = NOUT / 2;
  float a0 = 0.f, a1 = 0.f;
  for (int half = 0; half < 2; ++half) {
    __syncthreads();
#pragma unroll
    for (int q = 0; q < 4; ++q) {
      int flat = (q * 512 + t) * 4;
      int r = flat >> 9, c = flat & 511;
      *(float4*)&xs[flat] =
          *(const float4*)&p.x[(size_t)(rbase + r) * KIN + half * 512 + c];
    }
    __syncthreads();
    const float* x0 = xs + row * 512;
    const float2* Wp = W2 + (size_t)(half * 512) * S + wcol;
    float2 b0[4], b1[4], n0[4], n1[4];
#pragma unroll
    for (int j = 0; j < 4; ++j) { b0[j] = Wp[(size_t)j * S]; b1[j] = Wp[(size_t)(4 + j) * S]; }
    int k = 0;
    for (; k + 16 <= 512; k += 8) {
#pragma unroll
      for (int j = 0; j < 4; ++j) n0[j] = Wp[(size_t)(k + 8 + j) * S];
#pragma unroll
      for (int j = 0; j < 4; ++j) n1[j] = Wp[(size_t)(k + 12 + j) * S];
      float4 xa = *(const float4*)&x0[k];
      a0 += xa.x * b0[0].x; a1 += xa.x * b0[0].y;
      a0 += xa.y * b0[1].x; a1 += xa.y * b0[1].y;
      a0 += xa.z * b0[2].x; a1 += xa.z * b0[2].y;
      a0 += xa.w * b0[3].x; a1 += xa.w * b0[3].y;
      float4 xb = *(const float4*)&x0[k + 4];
      a0 += xb.x * b1[0].x; a1 += xb.x * b1[0].y;
      a0 += xb.y * b1[1].x; a1 += xb.y * b1[1].y;
      a0 += xb.z * b1[2].x; a1 += xb.z * b1[2].y;
      a0 += xb.w * b1[3].x; a1 += xb.w * b1[3].y;
#pragma unroll
      for (int j = 0; j < 4; ++j) { b0[j] = n0[j]; b1[j] = n1[j]; }
    }
    {  // tail: consume last two prefetched batches (k = 496..511)
      float4 xa = *(const float4*)&x0[k];
      a0 += xa.x * b0[0].x; a1 += xa.x * b0[0].y;
      a0 += xa.y * b0[1].x; a1 += xa.y * b0[1].y;
      a0 += xa.z * b0[2].x; a1 += xa.z * b0[2].y;
      a0 += xa.w * b0[3].x; a1 += xa.w * b0[3].y;
      float4 xb = *(const float4*)&x0[k + 4];
      a0 += xb.x * b1[0].x; a1 += xb.x * b1[0].y;
      a0 += xb.y * b1[1].x; a1 += xb.y * b1[1].y;
      a0 += xb.z * b1[2].x; a1 += xb.z * b1[2].y;
      a0 += xb.w * b1[3].x; a1 += xb.w * b1[3].y;
    }
  }
  float2 bc = *(const float2*)&p.bc1[cg];
  nt_store2(&p.h[(size_t)(rbase + row) * NOUT + cg], gelu_f(a0 + bc.x), gelu_f(a1 + bc.y));
}

// ---- GEMM2: ct = h @ Wc2 + bc2; K=2048 in 4 LDS-staged quarters; prefetch x2
__device__ void g2_phase(const Par& p, float* smem) {
  int b = blockIdx.x, t = threadIdx.x;
  int mt = b >> 5, nc = b & 31;
  int rbase = mt * 16, cbase = nc * 64;
  float* hs = smem;  // [16][512]
  int row = t >> 5;
  int cg = cbase + (t & 31) * 2;
  int wcol = cg >> 1;
  const float2* W2 = (const float2*)p.Wc2;
  const int S = NOUT / 2;
  float a0 = 0.f, a1 = 0.f;
  for (int qtr = 0; qtr < 4; ++qtr) {
    __syncthreads();
#pragma unroll
    for (int q = 0; q < 4; ++q) {
      int flat = (q * 512 + t) * 4;
      int r = flat >> 9, c = flat & 511;
      *(float4*)&hs[flat] =
          nt_load4(&p.h[(size_t)(rbase + r) * NOUT + qtr * 512 + c]);
    }
    __syncthreads();
    const float* x0 = hs + row * 512;
    const float2* Wp = W2 + (size_t)(qtr * 512) * S + wcol;
    float2 b0[4], b1[4], n0[4], n1[4];
#pragma unroll
    for (int j = 0; j < 4; ++j) { b0[j] = Wp[(size_t)j * S]; b1[j] = Wp[(size_t)(4 + j) * S]; }
    int k = 0;
    for (; k + 16 <= 512; k += 8) {
#pragma unroll
      for (int j = 0; j < 4; ++j) n0[j] = Wp[(size_t)(k + 8 + j) * S];
#pragma unroll
      for (int j = 0; j < 4; ++j) n1[j] = Wp[(size_t)(k + 12 + j) * S];
      float4 xa = *(const float4*)&x0[k];
      a0 += xa.x * b0[0].x; a1 += xa.x * b0[0].y;
      a0 += xa.y * b0[1].x; a1 += xa.y * b0[1].y;
      a0 += xa.z * b0[2].x; a1 += xa.z * b0[2].y;
      a0 += xa.w * b0[3].x; a1 += xa.w * b0[3].y;
      float4 xb = *(const float4*)&x0[k + 4];
      a0 += xb.x * b1[0].x; a1 += xb.x * b1[0].y;
      a0 += xb.y * b1[1].x; a1 += xb.y * b1[1].y;
      a0 += xb.z * b1[2].x; a1 += xb.z * b1[2].y;
      a0 += xb.w * b1[3].x; a1 += xb.w * b1[3].y;
#pragma unroll
      for (int j = 0; j < 4; ++j) { b0[j] = n0[j]; b1[j] = n1[j]; }
    }
    {
      float4 xa = *(const float4*)&x0[k];
      a0 += xa.x * b0[0].x; a1 += xa.x * b0[0].y;
      a0 += xa.y * b0[1].x; a1 += xa.y * b0[1].y;
      a0 += xa.z * b0[2].x; a1 += xa.z * b0[2].y;
      a0 += xa.w * b0[3].x; a1 += xa.w * b0[3].y;
      float4 xb = *(const float4*)&x0[k + 4];
      a0 += xb.x * b1[0].x; a1 += xb.x * b1[0].y;
      a0 += xb.y * b1[1].x; a1 += xb.y * b1[1].y;
      a0 += xb.z * b1[2].x; a1 += xb.z * b1[2].y;
      a0 += xb.w * b1[3].x; a1 += xb.w * b1[3].y;
    }
  }
  float2 bc = *(const float2*)&p.bc2[cg];
  nt_store2(&p.ct[(size_t)(rbase + row) * NOUT + cg], a0 + bc.x, a1 + bc.y);
}

// ---- EPI: gates/blend/LN -> cs[slot_new]; recompute logits for pairs k-1, k
__device__ void epi_phase(const Par& p, int i, float* smem, float* sred) {
  int n = blockIdx.x;
  int t = threadIdx.x, wave = t >> 6, lane = t & 63;
  int Pn = 62 - i;
  int k = p.ksel[n];
  int slot_new = p.pos[n * 64 + k];
  float* s_wd1 = smem;          // [0, 8192)
  float* sx = smem + 8192;      // x-row stash from sel (1024 floats)
  float* s_wd2 = smem + 9216;   // 64
  float* s_bd1 = smem + 9280;   // 64
  float* s_fnew = smem + 9344;  // 64
  if (i < 62) {
#pragma unroll
    for (int q = 0; q < 4; ++q)
      ((float4*)s_wd1)[q * 512 + t] = ((const float4*)p.Wd1)[q * 512 + t];
    if (t < 64) { s_wd2[t] = p.Wd2[t]; s_bd1[t] = p.bd1[t]; }
  }
  const float* ct = p.ct + (size_t)n * NOUT;
  int d = t;  // 512 threads = 512 dims
  float lv = sx[d];
  float rv = sx[512 + d];
  float c0 = nt_load1(&ct[d]);
  float c1 = nt_load1(&ct[DMODEL + d]);
  float c2 = nt_load1(&ct[2 * DMODEL + d]);
  float c3 = nt_load1(&ct[3 * DMODEL + d]);
  float s = sigm_f(c0) * lv + sigm_f(c1) * rv + sigm_f(c2) * c3;
  float part = wred_sum(s);
  if (lane == 0) sred[wave] = part;
  __syncthreads();
  float m = 0.f;
#pragma unroll
  for (int w = 0; w < 8; ++w) m += sred[w];
  m *= (1.0f / 512.0f);
  float e = s - m;
  float pq = wred_sum(e * e);
  if (lane == 0) sred[8 + wave] = pq;
  __syncthreads();
  float var = 0.f;
#pragma unroll
  for (int w = 0; w < 8; ++w) var += sred[8 + w];
  var *= (1.0f / 512.0f);
  float inv = 1.0f / sqrtf(var + 1e-5f);
  float nv = e * inv * p.gc[d] + p.btc[d];
  p.cs[(size_t)(n * 64 + slot_new) * DMODEL + d] = nv;
  if (i == 62) p.out[(size_t)n * DMODEL + d] = nv;
  if (d < FDIM) s_fnew[d] = nv;
  __syncthreads();
  if (i < 62) {
    if (wave == 0 && k >= 1) {
      const float* A = &p.cs[(size_t)(n * 64 + p.pos[n * 64 + (k - 1)]) * DMODEL];
      float hs = s_bd1[lane];
#pragma unroll 8
      for (int kk = 0; kk < 64; ++kk) hs += A[kk] * s_wd1[kk * 64 + lane];
#pragma unroll 8
      for (int kk = 0; kk < 64; ++kk) hs += s_fnew[kk] * s_wd1[(64 + kk) * 64 + lane];
      float g = wred_sum(gelu_f(hs) * s_wd2[lane]);
      if (lane == 0) p.logits[n * 64 + (k - 1)] = g + p.bd2[0];
    } else if (wave == 1 && k < Pn) {
      const float* Bv = &p.cs[(size_t)(n * 64 + p.pos[n * 64 + (k + 1)]) * DMODEL];
      float hs = s_bd1[lane];
#pragma unroll 8
      for (int kk = 0; kk < 64; ++kk) hs += s_fnew[kk] * s_wd1[kk * 64 + lane];
#pragma unroll 8
      for (int kk = 0; kk < 64; ++kk) hs += Bv[kk] * s_wd1[(64 + kk) * 64 + lane];
      float g = wred_sum(gelu_f(hs) * s_wd2[lane]);
      if (lane == 0) p.logits[n * 64 + k] = g + p.bd2[0];
    }
  }
}

__global__ void egt_zero(unsigned int* bar) { bar[threadIdx.x] = 0u; }

__global__ void __launch_bounds__(512, 2) egt_main(Par p) {
  __shared__ __align__(16) float smem[12480];  // 49.9 KB
  __shared__ float sred[16];
  __shared__ int sI[8];
  unsigned int nsync = 0;
  int b = blockIdx.x, t = threadIdx.x;
  int wave = t >> 6, lane = t & 63;

  // ---------- INIT-PROJ: cs0 = LN(input @ Wi + bi); 32 (n,s)-rows per block
  {
    int rbase = b * 32;
    int n_ = b >> 1;
    float acc[32];
#pragma unroll
    for (int r = 0; r < 32; ++r) acc[r] = 0.f;
    float* xs = smem;  // [32][64]
    const float* Wi = p.Wi;
    for (int kc = 0; kc < 512; kc += 64) {
      __syncthreads();
      {
        int flat = t * 4;
        int r = flat >> 6, c = flat & 63;
        *(float4*)&xs[flat] =
            nt_load4(&p.input[(size_t)(rbase + r) * 512 + kc + c]);
      }
      __syncthreads();
      for (int k = 0; k < 64; k += 4) {
        float w0 = Wi[(size_t)(kc + k + 0) * 512 + t];
        float w1 = Wi[(size_t)(kc + k + 1) * 512 + t];
        float w2 = Wi[(size_t)(kc + k + 2) * 512 + t];
        float w3 = Wi[(size_t)(kc + k + 3) * 512 + t];
#pragma unroll
        for (int r = 0; r < 32; ++r) {
          float4 xv = *(const float4*)&xs[r * 64 + k];
          acc[r] += xv.x * w0 + xv.y * w1 + xv.z * w2 + xv.w * w3;
        }
      }
    }
    float* row8 = smem;  // [8][512]
#pragma unroll
    for (int chunk = 0; chunk < 4; ++chunk) {
      __syncthreads();
#pragma unroll
      for (int rr = 0; rr < 8; ++rr)
        row8[rr * 512 + t] = acc[chunk * 8 + rr] + p.bi[t];
      __syncthreads();
      int rr = wave;
      float vals[8];
      float sum = 0.f;
#pragma unroll
      for (int jj = 0; jj < 8; ++jj) {
        float v = row8[rr * 512 + jj * 64 + lane];
        vals[jj] = v;
        sum += v;
      }
      sum = wred_sum(sum);
      float mm = sum * (1.0f / 512.0f);
      float sq = 0.f;
#pragma unroll
      for (int jj = 0; jj < 8; ++jj) { float dd = vals[jj] - mm; sq += dd * dd; }
      sq = wred_sum(sq);
      float inv = 1.0f / sqrtf(sq * (1.0f / 512.0f) + 1e-5f);
      int r = chunk * 8 + rr;
      int ss = (b & 1) * 32 + r;
      float* dst = &p.cs[(size_t)(n_ * 64 + ss) * DMODEL];
#pragma unroll
      for (int jj = 0; jj < 8; ++jj) {
        int c = jj * 64 + lane;
        dst[c] = (vals[jj] - mm) * inv * p.gi[c] + p.bti[c];
      }
    }
  }
  gsync(p.bar, &nsync);

  // ---------- INIT-SCORE: 63 pair logits per row; init pos; SEL(0)
  if (b < NBATCH) {
    int n = b;
    float* s_wd1 = smem;          // 8192 floats
    float* s_f = smem + 8192;     // 4096 floats: 64 slots x first-64 dims
    float* s_wd2 = smem + 12288;  // 64
    float* s_bd1 = smem + 12352;  // 64
#pragma unroll
    for (int q = 0; q < 4; ++q)
      ((float4*)s_wd1)[q * 512 + t] = ((const float4*)p.Wd1)[q * 512 + t];
#pragma unroll
    for (int q = 0; q < 2; ++q) {
      int i4 = q * 512 + t;
      int s = i4 >> 4, c = (i4 & 15) * 4;
      *(float4*)&s_f[s * 64 + c] =
          *(const float4*)&p.cs[(size_t)(n * 64 + s) * DMODEL + c];
    }
    if (t < 64) {
      s_wd2[t] = p.Wd2[t];
      s_bd1[t] = p.bd1[t];
      p.pos[n * 64 + t] = t;
    }
    __syncthreads();
    for (int pr = wave; pr < 63; pr += 8) {
      float hs = s_bd1[lane];
#pragma unroll 8
      for (int kk = 0; kk < 64; ++kk) hs += s_f[pr * 64 + kk] * s_wd1[kk * 64 + lane];
#pragma unroll 8
      for (int kk = 0; kk < 64; ++kk) hs += s_f[(pr + 1) * 64 + kk] * s_wd1[(64 + kk) * 64 + lane];
      float g = wred_sum(gelu_f(hs) * s_wd2[lane]);
      if (lane == 0) p.logits[n * 64 + pr] = g + p.bd2[0];
    }
    __syncthreads();
    sel_phase(p, 0, sI, smem);
  }
  gsync(p.bar, &nsync);

  // ---------- main serial loop
  for (int i = 0; i < 63; ++i) {
    g1_phase(p, smem);
    gsync(p.bar, &nsync);
    g2_phase(p, smem);
    gsync(p.bar, &nsync);
    if (b < NBATCH) {
      epi_phase(p, i, smem, sred);
      if (i < 62) {
        __syncthreads();
        sel_phase(p, i + 1, sI, smem);
      }
    }
    gsync(p.bar, &nsync);
  }
}

extern "C" void kernel_launch(void* const* d_in, const int* in_sizes, int n_in,
                              void* d_out, int out_size, void* d_ws, size_t ws_size,
                              hipStream_t stream) {
  Par p;
  p.input = (const float*)d_in[0];
  p.mask = (const float*)d_in[1];
  p.Wi = (const float*)d_in[2];
  p.bi = (const float*)d_in[3];
  p.gi = (const float*)d_in[4];
  p.bti = (const float*)d_in[5];
  p.Wd1 = (const float*)d_in[6];
  p.bd1 = (const float*)d_in[7];
  p.Wd2 = (const float*)d_in[8];
  p.bd2 = (const float*)d_in[9];
  p.Wc1 = (const float*)d_in[10];
  p.bc1 = (const float*)d_in[11];
  p.Wc2 = (const float*)d_in[12];
  p.bc2 = (const float*)d_in[13];
  p.gc = (const float*)d_in[14];
  p.btc = (const float*)d_in[15];
  p.out = (float*)d_out;

  float* ws = (float*)d_ws;
  size_t off = 0;
  p.bar = (unsigned int*)(ws + off); off += 256;
  p.pos = (int*)(ws + off); off += 128 * 64;
  p.ksel = (int*)(ws + off); off += 128;
  off = (off + 127) & ~(size_t)127;
  p.logits = ws + off; off += 128 * 64;
  p.x = ws + off; off += (size_t)128 * 1024;
  p.h = ws + off; off += (size_t)128 * 2048;
  p.ct = ws + off; off += (size_t)128 * 2048;
  p.cs = ws + off; off += (size_t)128 * 64 * 512;

  hipLaunchKernelGGL(egt_zero, dim3(1), dim3(256), 0, stream, p.bar);
  void* args[] = {&p};
  hipError_t err = hipLaunchCooperativeKernel(egt_main, dim3(256), dim3(512), args, 0, stream);
  if (err != hipSuccess) {
    (void)hipGetLastError();  // manual barrier works under plain launch too
    hipLaunchKernelGGL(egt_main, dim3(256), dim3(512), 0, stream, p);
  }
}

// Round 6
// 9772.427 us; speedup vs baseline: 1.5398x; 1.5398x over previous
//
#include <hip/hip_runtime.h>

#define NBATCH 128
#define DMODEL 512
#define FDIM 64
#define KIN 1024
#define NOUT 2048

struct Par {
  const float *input, *mask, *Wi, *bi, *gi, *bti;
  const float *Wd1, *bd1, *Wd2, *bd2;
  const float *Wc1, *bc1, *Wc2, *bc2, *gc, *btc;
  float *out;
  float *cs, *x, *h, *ct, *logits;
  int *pos, *ksel;
  unsigned int *bar;
};

__device__ __forceinline__ float gelu_f(float v) {
  float u = 0.7978845608028654f * (v + 0.044715f * v * v * v);
  return 0.5f * v * (1.0f + tanhf(u));
}
__device__ __forceinline__ float sigm_f(float v) { return 1.0f / (1.0f + expf(-v)); }

__device__ __forceinline__ float wred_sum(float v) {
#pragma unroll
  for (int o = 32; o > 0; o >>= 1) v += __shfl_xor(v, o, 64);
  return v;
}

// monotonic-counter grid barrier (256 co-resident blocks)
__device__ __forceinline__ void gsync(unsigned int* bar, unsigned int* tgt) {
  __syncthreads();
  if (threadIdx.x == 0) {
    *tgt += gridDim.x;
    __hip_atomic_fetch_add(bar, 1u, __ATOMIC_ACQ_REL, __HIP_MEMORY_SCOPE_AGENT);
    while (__hip_atomic_load(bar, __ATOMIC_ACQUIRE, __HIP_MEMORY_SCOPE_AGENT) < *tgt)
      __builtin_amdgcn_s_sleep(1);
  }
  __syncthreads();
}

// ---- SEL: argmax + pos/logit shift + build x = [l_sel, r_sel]; stash x-row in LDS
__device__ void sel_phase(const Par& p, int i, int* sI, float* smem) {
  int n = blockIdx.x;
  int t = threadIdx.x, wave = t >> 6, lane = t & 63;
  int P = 63 - i;
  if (wave == 0) {
    float v = -3.0e38f;
    int idx = 1 << 20;
    if (lane < P) {
      v = p.logits[n * 64 + lane];
      float mk = p.mask[n * 64 + i + 1 + lane];
      if (!(mk > 0.0f)) v = -1.0e9f;
      idx = lane;
    }
#pragma unroll
    for (int o = 32; o > 0; o >>= 1) {
      float v2 = __shfl_xor(v, o, 64);
      int i2 = __shfl_xor(idx, o, 64);
      if (v2 > v || (v2 == v && i2 < idx)) { v = v2; idx = i2; }
    }
    if (lane == 0) {
      p.ksel[n] = idx;
      sI[0] = idx;
      sI[1] = p.pos[n * 64 + idx];
      sI[2] = p.pos[n * 64 + idx + 1];
    }
  }
  __syncthreads();
  int k = sI[0], slot_l = sI[1], slot_r = sI[2];
  if (wave == 1) {  // shift pos (wave-lockstep load-before-store)
    int j = lane;
    if (j >= k + 1 && j <= 62 - i) {
      int tmp = p.pos[n * 64 + j + 1];
      p.pos[n * 64 + j] = tmp;
    }
  } else if (wave == 2) {  // shift logits
    int j = lane;
    if (j >= k && j <= 61 - i) {
      float tmp = p.logits[n * 64 + j + 1];
      p.logits[n * 64 + j] = tmp;
    }
  }
  const float* csl = &p.cs[(size_t)(n * 64 + slot_l) * DMODEL];
  const float* csr = &p.cs[(size_t)(n * 64 + slot_r) * DMODEL];
  float* xg = &p.x[(size_t)n * KIN];
  float* sx = smem + 11456;  // persists through g1/g2 (they use [0,10560))
  if (t < 128) {
    float4 v = *(const float4*)&csl[t * 4];
    *(float4*)&xg[t * 4] = v;
    *(float4*)&sx[t * 4] = v;
  } else if (t < 256) {
    float4 v = *(const float4*)&csr[(t - 128) * 4];
    *(float4*)&xg[512 + (t - 128) * 4] = v;
    *(float4*)&sx[512 + (t - 128) * 4] = v;
  }
}

// ---- LDS-tiled GEMM: Y[M=128][2048] = act(X[M][K] @ W[K][2048] + bias)
// block: rg = 64-row half, cg = 16-col group (XCD-pinned: cg = (b&7)*16 + (b>>4))
// K chunked at 128; x-tile [64][132] + W-tile(T) [16][132] in LDS; reg double-buffer
__device__ void gemm_tiled(const float* X, const float* Wg, const float* bias,
                           float* Y, int K, bool do_gelu, float* smem) {
  int b = blockIdx.x, t = threadIdx.x;
  int xcd = b & 7;
  int u = b >> 3;
  int rg = u & 1, j = u >> 1;
  int cg = xcd * 16 + j;  // 0..127; each XCD owns contiguous 256 W-cols (~3MB, L2-resident)
  int rbase = rg * 64, cbase = cg * 16;
  float* xs = smem;            // [64][132]
  float* wt = smem + 64 * 132; // [16][132] transposed W chunk
  int NC = K >> 7;
  // staging indices: x: 4 float4/thread; W: 1 float4/thread (transposed into LDS)
  int srow[4], sc4[4];
#pragma unroll
  for (int q = 0; q < 4; ++q) {
    int idx = q * 512 + t;
    srow[q] = idx >> 5;
    sc4[q] = (idx & 31) * 4;
  }
  int krow = t >> 2, cq = (t & 3) * 4;
  // compute indices: 2 rows x 1 col per thread
  int c = t & 15, rp = t >> 4;
  int r0 = rp * 2, r1 = r0 + 1;
  float4 xr[4], wr;
#pragma unroll
  for (int q = 0; q < 4; ++q)
    xr[q] = *(const float4*)&X[(size_t)(rbase + srow[q]) * K + sc4[q]];
  wr = *(const float4*)&Wg[(size_t)krow * NOUT + cbase + cq];
  float a0 = 0.f, a1 = 0.f;
  for (int ch = 0; ch < NC; ++ch) {
    __syncthreads();  // previous chunk's readers done
#pragma unroll
    for (int q = 0; q < 4; ++q) *(float4*)&xs[srow[q] * 132 + sc4[q]] = xr[q];
    wt[(cq + 0) * 132 + krow] = wr.x;
    wt[(cq + 1) * 132 + krow] = wr.y;
    wt[(cq + 2) * 132 + krow] = wr.z;
    wt[(cq + 3) * 132 + krow] = wr.w;
    __syncthreads();  // tiles visible
    if (ch + 1 < NC) {  // prefetch next chunk into regs (overlaps compute)
      int k0 = (ch + 1) << 7;
#pragma unroll
      for (int q = 0; q < 4; ++q)
        xr[q] = *(const float4*)&X[(size_t)(rbase + srow[q]) * K + k0 + sc4[q]];
      wr = *(const float4*)&Wg[(size_t)(k0 + krow) * NOUT + cbase + cq];
    }
    const float* xp0 = xs + r0 * 132;
    const float* xp1 = xs + r1 * 132;
    const float* wp = wt + c * 132;
#pragma unroll 4
    for (int k4 = 0; k4 < 128; k4 += 4) {
      float4 xa = *(const float4*)&xp0[k4];
      float4 xb = *(const float4*)&xp1[k4];
      float4 wv = *(const float4*)&wp[k4];
      a0 += xa.x * wv.x; a1 += xb.x * wv.x;
      a0 += xa.y * wv.y; a1 += xb.y * wv.y;
      a0 += xa.z * wv.z; a1 += xb.z * wv.z;
      a0 += xa.w * wv.w; a1 += xb.w * wv.w;
    }
  }
  float bb = bias[cbase + c];
  float o0 = a0 + bb, o1 = a1 + bb;
  if (do_gelu) { o0 = gelu_f(o0); o1 = gelu_f(o1); }
  Y[(size_t)(rbase + r0) * NOUT + cbase + c] = o0;
  Y[(size_t)(rbase + r1) * NOUT + cbase + c] = o1;
}

// ---- EPI: gates/blend/LN -> cs[slot_new]; recompute logits for pairs k-1, k
__device__ void epi_phase(const Par& p, int i, float* smem, float* sred) {
  int n = blockIdx.x;
  int t = threadIdx.x, wave = t >> 6, lane = t & 63;
  int Pn = 62 - i;
  int k = p.ksel[n];
  int slot_new = p.pos[n * 64 + k];
  float* s_wd1 = smem;          // [0, 8192)
  float* s_wd2 = smem + 8192;   // 64
  float* s_bd1 = smem + 8256;   // 64
  float* s_fnew = smem + 8320;  // 64
  float* sx = smem + 11456;     // x-row stash from sel (survived g1/g2)
  if (i < 62) {
#pragma unroll
    for (int q = 0; q < 4; ++q)
      ((float4*)s_wd1)[q * 512 + t] = ((const float4*)p.Wd1)[q * 512 + t];
    if (t < 64) { s_wd2[t] = p.Wd2[t]; s_bd1[t] = p.bd1[t]; }
  }
  const float* ct = p.ct + (size_t)n * NOUT;
  int d = t;
  float lv = sx[d];
  float rv = sx[512 + d];
  float c0 = ct[d], c1 = ct[DMODEL + d], c2 = ct[2 * DMODEL + d], c3 = ct[3 * DMODEL + d];
  float s = sigm_f(c0) * lv + sigm_f(c1) * rv + sigm_f(c2) * c3;
  float part = wred_sum(s);
  if (lane == 0) sred[wave] = part;
  __syncthreads();
  float m = 0.f;
#pragma unroll
  for (int w = 0; w < 8; ++w) m += sred[w];
  m *= (1.0f / 512.0f);
  float e = s - m;
  float pq = wred_sum(e * e);
  if (lane == 0) sred[8 + wave] = pq;
  __syncthreads();
  float var = 0.f;
#pragma unroll
  for (int w = 0; w < 8; ++w) var += sred[8 + w];
  var *= (1.0f / 512.0f);
  float inv = 1.0f / sqrtf(var + 1e-5f);
  float nv = e * inv * p.gc[d] + p.btc[d];
  p.cs[(size_t)(n * 64 + slot_new) * DMODEL + d] = nv;
  if (i == 62) p.out[(size_t)n * DMODEL + d] = nv;
  if (d < FDIM) s_fnew[d] = nv;
  __syncthreads();
  if (i < 62) {
    if (wave == 0 && k >= 1) {
      const float* A = &p.cs[(size_t)(n * 64 + p.pos[n * 64 + (k - 1)]) * DMODEL];
      float hs = s_bd1[lane];
#pragma unroll 8
      for (int kk = 0; kk < 64; ++kk) hs += A[kk] * s_wd1[kk * 64 + lane];
#pragma unroll 8
      for (int kk = 0; kk < 64; ++kk) hs += s_fnew[kk] * s_wd1[(64 + kk) * 64 + lane];
      float g = wred_sum(gelu_f(hs) * s_wd2[lane]);
      if (lane == 0) p.logits[n * 64 + (k - 1)] = g + p.bd2[0];
    } else if (wave == 1 && k < Pn) {
      const float* Bv = &p.cs[(size_t)(n * 64 + p.pos[n * 64 + (k + 1)]) * DMODEL];
      float hs = s_bd1[lane];
#pragma unroll 8
      for (int kk = 0; kk < 64; ++kk) hs += s_fnew[kk] * s_wd1[kk * 64 + lane];
#pragma unroll 8
      for (int kk = 0; kk < 64; ++kk) hs += Bv[kk] * s_wd1[(64 + kk) * 64 + lane];
      float g = wred_sum(gelu_f(hs) * s_wd2[lane]);
      if (lane == 0) p.logits[n * 64 + k] = g + p.bd2[0];
    }
  }
}

__global__ void egt_zero(unsigned int* bar) { bar[threadIdx.x] = 0u; }

__global__ void __launch_bounds__(512, 2) egt_main(Par p) {
  __shared__ __align__(16) float smem[12480];  // 48.75 KB
  __shared__ float sred[16];
  __shared__ int sI[8];
  unsigned int nsync = 0;
  int b = blockIdx.x, t = threadIdx.x;
  int wave = t >> 6, lane = t & 63;

  // ---------- INIT-PROJ: cs0 = LN(input @ Wi + bi); 32 (n,s)-rows per block
  {
    int rbase = b * 32;
    int n_ = b >> 1;
    float acc[32];
#pragma unroll
    for (int r = 0; r < 32; ++r) acc[r] = 0.f;
    float* xs = smem;  // [32][64]
    const float* Wi = p.Wi;
    for (int kc = 0; kc < 512; kc += 64) {
      __syncthreads();
      {
        int flat = t * 4;
        int r = flat >> 6, c = flat & 63;
        *(float4*)&xs[flat] =
            *(const float4*)&p.input[(size_t)(rbase + r) * 512 + kc + c];
      }
      __syncthreads();
      for (int k = 0; k < 64; k += 4) {
        float w0 = Wi[(size_t)(kc + k + 0) * 512 + t];
        float w1 = Wi[(size_t)(kc + k + 1) * 512 + t];
        float w2 = Wi[(size_t)(kc + k + 2) * 512 + t];
        float w3 = Wi[(size_t)(kc + k + 3) * 512 + t];
#pragma unroll
        for (int r = 0; r < 32; ++r) {
          float4 xv = *(const float4*)&xs[r * 64 + k];
          acc[r] += xv.x * w0 + xv.y * w1 + xv.z * w2 + xv.w * w3;
        }
      }
    }
    float* row8 = smem;  // [8][512]
#pragma unroll
    for (int chunk = 0; chunk < 4; ++chunk) {
      __syncthreads();
#pragma unroll
      for (int rr = 0; rr < 8; ++rr)
        row8[rr * 512 + t] = acc[chunk * 8 + rr] + p.bi[t];
      __syncthreads();
      int rr = wave;
      float vals[8];
      float sum = 0.f;
#pragma unroll
      for (int jj = 0; jj < 8; ++jj) {
        float v = row8[rr * 512 + jj * 64 + lane];
        vals[jj] = v;
        sum += v;
      }
      sum = wred_sum(sum);
      float mm = sum * (1.0f / 512.0f);
      float sq = 0.f;
#pragma unroll
      for (int jj = 0; jj < 8; ++jj) { float dd = vals[jj] - mm; sq += dd * dd; }
      sq = wred_sum(sq);
      float inv = 1.0f / sqrtf(sq * (1.0f / 512.0f) + 1e-5f);
      int r = chunk * 8 + rr;
      int ss = (b & 1) * 32 + r;
      float* dst = &p.cs[(size_t)(n_ * 64 + ss) * DMODEL];
#pragma unroll
      for (int jj = 0; jj < 8; ++jj) {
        int c = jj * 64 + lane;
        dst[c] = (vals[jj] - mm) * inv * p.gi[c] + p.bti[c];
      }
    }
  }
  gsync(p.bar, &nsync);

  // ---------- INIT-SCORE: 63 pair logits per row; init pos; SEL(0)
  if (b < NBATCH) {
    int n = b;
    float* s_wd1 = smem;          // 8192 floats
    float* s_f = smem + 8192;     // 4096 floats: 64 slots x first-64 dims
    float* s_wd2 = smem + 12288;  // 64
    float* s_bd1 = smem + 12352;  // 64
#pragma unroll
    for (int q = 0; q < 4; ++q)
      ((float4*)s_wd1)[q * 512 + t] = ((const float4*)p.Wd1)[q * 512 + t];
#pragma unroll
    for (int q = 0; q < 2; ++q) {
      int i4 = q * 512 + t;
      int s = i4 >> 4, c = (i4 & 15) * 4;
      *(float4*)&s_f[s * 64 + c] =
          *(const float4*)&p.cs[(size_t)(n * 64 + s) * DMODEL + c];
    }
    if (t < 64) {
      s_wd2[t] = p.Wd2[t];
      s_bd1[t] = p.bd1[t];
      p.pos[n * 64 + t] = t;
    }
    __syncthreads();
    for (int pr = wave; pr < 63; pr += 8) {
      float hs = s_bd1[lane];
#pragma unroll 8
      for (int kk = 0; kk < 64; ++kk) hs += s_f[pr * 64 + kk] * s_wd1[kk * 64 + lane];
#pragma unroll 8
      for (int kk = 0; kk < 64; ++kk) hs += s_f[(pr + 1) * 64 + kk] * s_wd1[(64 + kk) * 64 + lane];
      float g = wred_sum(gelu_f(hs) * s_wd2[lane]);
      if (lane == 0) p.logits[n * 64 + pr] = g + p.bd2[0];
    }
    __syncthreads();
    sel_phase(p, 0, sI, smem);
  }
  gsync(p.bar, &nsync);

  // ---------- main serial loop
  for (int i = 0; i < 63; ++i) {
    gemm_tiled(p.x, p.Wc1, p.bc1, p.h, KIN, true, smem);
    gsync(p.bar, &nsync);
    gemm_tiled(p.h, p.Wc2, p.bc2, p.ct, NOUT, false, smem);
    gsync(p.bar, &nsync);
    if (b < NBATCH) {
      epi_phase(p, i, smem, sred);
      if (i < 62) {
        __syncthreads();
        sel_phase(p, i + 1, sI, smem);
      }
    }
    gsync(p.bar, &nsync);
  }
}

extern "C" void kernel_launch(void* const* d_in, const int* in_sizes, int n_in,
                              void* d_out, int out_size, void* d_ws, size_t ws_size,
                              hipStream_t stream) {
  Par p;
  p.input = (const float*)d_in[0];
  p.mask = (const float*)d_in[1];
  p.Wi = (const float*)d_in[2];
  p.bi = (const float*)d_in[3];
  p.gi = (const float*)d_in[4];
  p.bti = (const float*)d_in[5];
  p.Wd1 = (const float*)d_in[6];
  p.bd1 = (const float*)d_in[7];
  p.Wd2 = (const float*)d_in[8];
  p.bd2 = (const float*)d_in[9];
  p.Wc1 = (const float*)d_in[10];
  p.bc1 = (const float*)d_in[11];
  p.Wc2 = (const float*)d_in[12];
  p.bc2 = (const float*)d_in[13];
  p.gc = (const float*)d_in[14];
  p.btc = (const float*)d_in[15];
  p.out = (float*)d_out;

  float* ws = (float*)d_ws;
  size_t off = 0;
  p.bar = (unsigned int*)(ws + off); off += 256;
  p.pos = (int*)(ws + off); off += 128 * 64;
  p.ksel = (int*)(ws + off); off += 128;
  off = (off + 127) & ~(size_t)127;
  p.logits = ws + off; off += 128 * 64;
  p.x = ws + off; off += (size_t)128 * 1024;
  p.h = ws + off; off += (size_t)128 * 2048;
  p.ct = ws + off; off += (size_t)128 * 2048;
  p.cs = ws + off; off += (size_t)128 * 64 * 512;

  hipLaunchKernelGGL(egt_zero, dim3(1), dim3(256), 0, stream, p.bar);
  void* args[] = {&p};
  hipError_t err = hipLaunchCooperativeKernel(egt_main, dim3(256), dim3(512), args, 0, stream);
  if (err != hipSuccess) {
    (void)hipGetLastError();  // manual barrier works under plain launch too
    hipLaunchKernelGGL(egt_main, dim3(256), dim3(512), 0, stream, p);
  }
}

// Round 7
// 5276.627 us; speedup vs baseline: 2.8517x; 1.8520x over previous
//
#include <hip/hip_runtime.h>

#define NBATCH 128
#define DMODEL 512
#define FDIM 64
#define KIN 1024
#define NOUT 2048

typedef __attribute__((ext_vector_type(8))) short bf16x8;
typedef __attribute__((ext_vector_type(4))) float f32x4;

struct Par {
  const float *input, *mask, *Wi, *bi, *gi, *bti;
  const float *Wd1, *bd1, *Wd2, *bd2;
  const float *Wc1, *bc1, *Wc2, *bc2, *gc, *btc;
  float *out;
  float *cs, *ct, *logits;
  unsigned short *xhi, *xlo, *hhi, *hlo, *w1f, *w2f;
  int *pos, *ksel;
  unsigned int *bar;
};

#define W1PLANE 2097152u   // 128*32*512 u16 per plane
#define W2PLANE 4194304u   // 128*64*512 u16 per plane

__device__ __forceinline__ float gelu_f(float v) {
  float u = 0.7978845608028654f * (v + 0.044715f * v * v * v);
  return 0.5f * v * (1.0f + tanhf(u));
}
__device__ __forceinline__ float sigm_f(float v) { return 1.0f / (1.0f + expf(-v)); }

__device__ __forceinline__ float wred_sum(float v) {
#pragma unroll
  for (int o = 32; o > 0; o >>= 1) v += __shfl_xor(v, o, 64);
  return v;
}

__device__ __forceinline__ unsigned short bf16rn(float v) {
  unsigned int u = __float_as_uint(v);
  return (unsigned short)((u + 0x7FFFu + ((u >> 16) & 1u)) >> 16);
}
__device__ __forceinline__ float bf16hi_f(unsigned short h) {
  return __uint_as_float(((unsigned int)h) << 16);
}

// monotonic-counter grid barrier (256 co-resident blocks)
__device__ __forceinline__ void gsync(unsigned int* bar, unsigned int* tgt) {
  __syncthreads();
  if (threadIdx.x == 0) {
    *tgt += gridDim.x;
    __hip_atomic_fetch_add(bar, 1u, __ATOMIC_ACQ_REL, __HIP_MEMORY_SCOPE_AGENT);
    while (__hip_atomic_load(bar, __ATOMIC_ACQUIRE, __HIP_MEMORY_SCOPE_AGENT) < *tgt)
      __builtin_amdgcn_s_sleep(1);
  }
  __syncthreads();
}

// ---- SEL: argmax + pos/logit shift; emit x = [l,r] as bf16 hi/lo planes + LDS fp32 stash
__device__ void sel_phase(const Par& p, int i, int* sI, float* smem) {
  int n = blockIdx.x;
  int t = threadIdx.x, wave = t >> 6, lane = t & 63;
  int P = 63 - i;
  if (wave == 0) {
    float v = -3.0e38f;
    int idx = 1 << 20;
    if (lane < P) {
      v = p.logits[n * 64 + lane];
      float mk = p.mask[n * 64 + i + 1 + lane];
      if (!(mk > 0.0f)) v = -1.0e9f;
      idx = lane;
    }
#pragma unroll
    for (int o = 32; o > 0; o >>= 1) {
      float v2 = __shfl_xor(v, o, 64);
      int i2 = __shfl_xor(idx, o, 64);
      if (v2 > v || (v2 == v && i2 < idx)) { v = v2; idx = i2; }
    }
    if (lane == 0) {
      p.ksel[n] = idx;
      sI[0] = idx;
      sI[1] = p.pos[n * 64 + idx];
      sI[2] = p.pos[n * 64 + idx + 1];
    }
  }
  __syncthreads();
  int k = sI[0], slot_l = sI[1], slot_r = sI[2];
  if (wave == 1) {  // shift pos (wave-lockstep load-before-store)
    int j = lane;
    if (j >= k + 1 && j <= 62 - i) {
      int tmp = p.pos[n * 64 + j + 1];
      p.pos[n * 64 + j] = tmp;
    }
  } else if (wave == 2) {  // shift logits
    int j = lane;
    if (j >= k && j <= 61 - i) {
      float tmp = p.logits[n * 64 + j + 1];
      p.logits[n * 64 + j] = tmp;
    }
  }
  float* sx = smem + 12544;  // survives g1/g2 (they use floats [0,12544))
  if (t < 256) {
    const float* srcp = (t < 128) ? &p.cs[(size_t)(n * 64 + slot_l) * DMODEL]
                                  : &p.cs[(size_t)(n * 64 + slot_r) * DMODEL];
    int so = (t & 127) * 4;
    int o = (t < 128) ? so : (512 + so);
    float4 v = *(const float4*)&srcp[so];
    *(float4*)&sx[o] = v;
    ushort4 hi, lo;
    hi.x = bf16rn(v.x); lo.x = bf16rn(v.x - bf16hi_f(hi.x));
    hi.y = bf16rn(v.y); lo.y = bf16rn(v.y - bf16hi_f(hi.y));
    hi.z = bf16rn(v.z); lo.z = bf16rn(v.z - bf16hi_f(hi.z));
    hi.w = bf16rn(v.w); lo.w = bf16rn(v.w - bf16hi_f(hi.w));
    *(ushort4*)&p.xhi[(size_t)n * KIN + o] = hi;
    *(ushort4*)&p.xlo[(size_t)n * KIN + o] = lo;
  }
}

// ---- split-bf16 MFMA GEMM: Y[128][2048] = act(X[128][K] @ W[K][2048] + bias)
// 1024 16x16 tiles; block b -> Mtile m=(b>>3)&7, Ngroup ng=((b>>6)<<3)|(b&7) (XCD-pinned)
// 8 waves = 4 tiles x 2 K-halves (split-K, LDS-reduced). A staged in LDS (pad 8),
// B-frags loaded straight from L2 (frag-major planes built in INIT).
__device__ void gemm_mfma(const unsigned short* Ahi, const unsigned short* Alo,
                          const unsigned short* Bf, unsigned int bplane,
                          const float* bias, int K, int KS, int NCH, bool do_gelu,
                          unsigned short* Yhi, unsigned short* Ylo, float* Yf32,
                          float* smem) {
  int b = blockIdx.x, t = threadIdx.x;
  int m = (b >> 3) & 7;
  int ng = ((b >> 6) << 3) | (b & 7);
  int rbase = m * 16;
  int w = t >> 6, lane = t & 63;
  int tile = w & 3, hv = w >> 2;
  int quad = lane >> 4, mr = lane & 15;
  int nt = ng * 4 + tile;
  int cbase = nt * 16;
  unsigned short* As = (unsigned short*)smem;  // [pl][hv][16][264] u16
  float* red = smem + 8448;                    // 4096 floats
  int KH = K >> 1;
  f32x4 acc = {0.f, 0.f, 0.f, 0.f};
  const unsigned short* bp0 = Bf + (size_t)nt * KS * 512 + lane * 8;
  const unsigned short* bp1 = bp0 + bplane;
  for (int ch = 0; ch < NCH; ++ch) {
    __syncthreads();
#pragma unroll
    for (int q = 0; q < 4; ++q) {  // stage A: 2 planes x 2 k-halves x 16 rows x 256
      int g = q * 512 + t;
      int pl = g >> 10, hh = (g >> 9) & 1, r = (g >> 5) & 15, kg = g & 31;
      const unsigned short* src = (pl ? Alo : Ahi) +
          (size_t)(rbase + r) * K + hh * KH + ch * 256 + kg * 8;
      uint4 v = *(const uint4*)src;
      *(uint4*)&As[((pl * 2 + hh) * 16 + r) * 264 + kg * 8] = v;
    }
    __syncthreads();
    int ks0 = hv * (KS >> 1) + ch * 8;
    const unsigned short* a0 = &As[(hv * 16 + mr) * 264 + quad * 8];
    const unsigned short* a1 = &As[((2 + hv) * 16 + mr) * 264 + quad * 8];
#pragma unroll
    for (int s = 0; s < 8; ++s) {
      bf16x8 ah = *(const bf16x8*)(a0 + s * 32);
      bf16x8 al = *(const bf16x8*)(a1 + s * 32);
      bf16x8 bh = *(const bf16x8*)(bp0 + (size_t)(ks0 + s) * 512);
      bf16x8 bl = *(const bf16x8*)(bp1 + (size_t)(ks0 + s) * 512);
      acc = __builtin_amdgcn_mfma_f32_16x16x32_bf16(ah, bh, acc, 0, 0, 0);
      acc = __builtin_amdgcn_mfma_f32_16x16x32_bf16(ah, bl, acc, 0, 0, 0);
      acc = __builtin_amdgcn_mfma_f32_16x16x32_bf16(al, bh, acc, 0, 0, 0);
    }
  }
  if (hv == 1) *(f32x4*)&red[(tile * 64 + lane) * 4] = acc;
  __syncthreads();
  if (hv == 0) {
    f32x4 o4 = *(const f32x4*)&red[(tile * 64 + lane) * 4];
    float bb = bias[cbase + mr];
#pragma unroll
    for (int r = 0; r < 4; ++r) {
      float o = acc[r] + o4[r] + bb;
      int row = rbase + quad * 4 + r;  // C/D: col=lane&15, row=quad*4+reg
      if (do_gelu) {
        o = gelu_f(o);
        unsigned short h = bf16rn(o);
        unsigned short l = bf16rn(o - bf16hi_f(h));
        Yhi[(size_t)row * NOUT + cbase + mr] = h;
        Ylo[(size_t)row * NOUT + cbase + mr] = l;
      } else {
        Yf32[(size_t)row * NOUT + cbase + mr] = o;
      }
    }
  }
}

// ---- EPI: gates/blend/LN -> cs[slot_new]; recompute logits for pairs k-1, k
__device__ void epi_phase(const Par& p, int i, float* smem, float* sred) {
  int n = blockIdx.x;
  int t = threadIdx.x, wave = t >> 6, lane = t & 63;
  int Pn = 62 - i;
  int k = p.ksel[n];
  int slot_new = p.pos[n * 64 + k];
  float* s_wd1 = smem;          // [0, 8192)
  float* s_wd2 = smem + 8192;   // 64
  float* s_bd1 = smem + 8256;   // 64
  float* s_fnew = smem + 8320;  // 64
  float* sx = smem + 12544;     // x-row stash from sel
  if (i < 62) {
#pragma unroll
    for (int q = 0; q < 4; ++q)
      ((float4*)s_wd1)[q * 512 + t] = ((const float4*)p.Wd1)[q * 512 + t];
    if (t < 64) { s_wd2[t] = p.Wd2[t]; s_bd1[t] = p.bd1[t]; }
  }
  const float* ct = p.ct + (size_t)n * NOUT;
  int d = t;
  float lv = sx[d];
  float rv = sx[512 + d];
  float c0 = ct[d], c1 = ct[DMODEL + d], c2 = ct[2 * DMODEL + d], c3 = ct[3 * DMODEL + d];
  float s = sigm_f(c0) * lv + sigm_f(c1) * rv + sigm_f(c2) * c3;
  float part = wred_sum(s);
  if (lane == 0) sred[wave] = part;
  __syncthreads();
  float mm = 0.f;
#pragma unroll
  for (int ww = 0; ww < 8; ++ww) mm += sred[ww];
  mm *= (1.0f / 512.0f);
  float e = s - mm;
  float pq = wred_sum(e * e);
  if (lane == 0) sred[8 + wave] = pq;
  __syncthreads();
  float var = 0.f;
#pragma unroll
  for (int ww = 0; ww < 8; ++ww) var += sred[8 + ww];
  var *= (1.0f / 512.0f);
  float inv = 1.0f / sqrtf(var + 1e-5f);
  float nv = e * inv * p.gc[d] + p.btc[d];
  p.cs[(size_t)(n * 64 + slot_new) * DMODEL + d] = nv;
  if (i == 62) p.out[(size_t)n * DMODEL + d] = nv;
  if (d < FDIM) s_fnew[d] = nv;
  __syncthreads();
  if (i < 62) {
    if (wave == 0 && k >= 1) {
      const float* A = &p.cs[(size_t)(n * 64 + p.pos[n * 64 + (k - 1)]) * DMODEL];
      float hs = s_bd1[lane];
#pragma unroll 8
      for (int kk = 0; kk < 64; ++kk) hs += A[kk] * s_wd1[kk * 64 + lane];
#pragma unroll 8
      for (int kk = 0; kk < 64; ++kk) hs += s_fnew[kk] * s_wd1[(64 + kk) * 64 + lane];
      float g = wred_sum(gelu_f(hs) * s_wd2[lane]);
      if (lane == 0) p.logits[n * 64 + (k - 1)] = g + p.bd2[0];
    } else if (wave == 1 && k < Pn) {
      const float* Bv = &p.cs[(size_t)(n * 64 + p.pos[n * 64 + (k + 1)]) * DMODEL];
      float hs = s_bd1[lane];
#pragma unroll 8
      for (int kk = 0; kk < 64; ++kk) hs += s_fnew[kk] * s_wd1[kk * 64 + lane];
#pragma unroll 8
      for (int kk = 0; kk < 64; ++kk) hs += Bv[kk] * s_wd1[(64 + kk) * 64 + lane];
      float g = wred_sum(gelu_f(hs) * s_wd2[lane]);
      if (lane == 0) p.logits[n * 64 + k] = g + p.bd2[0];
    }
  }
}

__global__ void egt_zero(unsigned int* bar) { bar[threadIdx.x] = 0u; }

__global__ void __launch_bounds__(512, 2) egt_main(Par p) {
  __shared__ __align__(16) float smem[15872];  // 62 KB
  __shared__ float sred[16];
  __shared__ int sI[8];
  unsigned int nsync = 0;
  int b = blockIdx.x, t = threadIdx.x;
  int wave = t >> 6, lane = t & 63;

  // ---------- INIT-WTRANSFORM: Wc1/Wc2 fp32 -> B-frag-major bf16 hi/lo planes
  // frag elem: value = W[ks*32 + (lane>>4)*8 + j][nt*16 + (lane&15)]
  {
    int tid = b * 512 + t;
    for (int it = tid; it < 786432; it += 131072) {
      const float* W;
      unsigned short *dh, *dl;
      int nt, ks, l, KS2;
      if (it < 262144) {
        W = p.Wc1; dh = p.w1f; dl = p.w1f + W1PLANE;
        nt = it >> 11; int r2 = it & 2047; ks = r2 >> 6; l = r2 & 63; KS2 = 32;
      } else {
        int rem = it - 262144;
        W = p.Wc2; dh = p.w2f; dl = p.w2f + W2PLANE;
        nt = rem >> 12; int r2 = rem & 4095; ks = r2 >> 6; l = r2 & 63; KS2 = 64;
      }
      int k0 = ks * 32 + (l >> 4) * 8;
      int n = nt * 16 + (l & 15);
      unsigned int hw[4], lw[4];
#pragma unroll
      for (int jj = 0; jj < 4; ++jj) {
        float v0 = W[(size_t)(k0 + 2 * jj) * NOUT + n];
        float v1 = W[(size_t)(k0 + 2 * jj + 1) * NOUT + n];
        unsigned short h0 = bf16rn(v0), h1 = bf16rn(v1);
        unsigned short l0 = bf16rn(v0 - bf16hi_f(h0));
        unsigned short l1 = bf16rn(v1 - bf16hi_f(h1));
        hw[jj] = (unsigned int)h0 | ((unsigned int)h1 << 16);
        lw[jj] = (unsigned int)l0 | ((unsigned int)l1 << 16);
      }
      size_t o = ((size_t)nt * KS2 + ks) * 512 + l * 8;
      uint4 H; H.x = hw[0]; H.y = hw[1]; H.z = hw[2]; H.w = hw[3];
      uint4 L; L.x = lw[0]; L.y = lw[1]; L.z = lw[2]; L.w = lw[3];
      *(uint4*)&dh[o] = H;
      *(uint4*)&dl[o] = L;
    }
  }

  // ---------- INIT-PROJ: cs0 = LN(input @ Wi + bi); 32 (n,s)-rows per block
  {
    int rbase = b * 32;
    int n_ = b >> 1;
    float acc[32];
#pragma unroll
    for (int r = 0; r < 32; ++r) acc[r] = 0.f;
    float* xs = smem;  // [32][64]
    const float* Wi = p.Wi;
    for (int kc = 0; kc < 512; kc += 64) {
      __syncthreads();
      {
        int flat = t * 4;
        int r = flat >> 6, c = flat & 63;
        *(float4*)&xs[flat] =
            *(const float4*)&p.input[(size_t)(rbase + r) * 512 + kc + c];
      }
      __syncthreads();
      for (int k = 0; k < 64; k += 4) {
        float w0 = Wi[(size_t)(kc + k + 0) * 512 + t];
        float w1 = Wi[(size_t)(kc + k + 1) * 512 + t];
        float w2 = Wi[(size_t)(kc + k + 2) * 512 + t];
        float w3 = Wi[(size_t)(kc + k + 3) * 512 + t];
#pragma unroll
        for (int r = 0; r < 32; ++r) {
          float4 xv = *(const float4*)&xs[r * 64 + k];
          acc[r] += xv.x * w0 + xv.y * w1 + xv.z * w2 + xv.w * w3;
        }
      }
    }
    float* row8 = smem;  // [8][512]
#pragma unroll
    for (int chunk = 0; chunk < 4; ++chunk) {
      __syncthreads();
#pragma unroll
      for (int rr = 0; rr < 8; ++rr)
        row8[rr * 512 + t] = acc[chunk * 8 + rr] + p.bi[t];
      __syncthreads();
      int rr = wave;
      float vals[8];
      float sum = 0.f;
#pragma unroll
      for (int jj = 0; jj < 8; ++jj) {
        float v = row8[rr * 512 + jj * 64 + lane];
        vals[jj] = v;
        sum += v;
      }
      sum = wred_sum(sum);
      float mm = sum * (1.0f / 512.0f);
      float sq = 0.f;
#pragma unroll
      for (int jj = 0; jj < 8; ++jj) { float dd = vals[jj] - mm; sq += dd * dd; }
      sq = wred_sum(sq);
      float inv = 1.0f / sqrtf(sq * (1.0f / 512.0f) + 1e-5f);
      int r = chunk * 8 + rr;
      int ss = (b & 1) * 32 + r;
      float* dst = &p.cs[(size_t)(n_ * 64 + ss) * DMODEL];
#pragma unroll
      for (int jj = 0; jj < 8; ++jj) {
        int c = jj * 64 + lane;
        dst[c] = (vals[jj] - mm) * inv * p.gi[c] + p.bti[c];
      }
    }
  }
  gsync(p.bar, &nsync);

  // ---------- INIT-SCORE: 63 pair logits per row; init pos; SEL(0)
  if (b < NBATCH) {
    int n = b;
    float* s_wd1 = smem;          // 8192 floats
    float* s_f = smem + 8192;     // 4096 floats
    float* s_wd2 = smem + 12288;  // 64
    float* s_bd1 = smem + 12352;  // 64
#pragma unroll
    for (int q = 0; q < 4; ++q)
      ((float4*)s_wd1)[q * 512 + t] = ((const float4*)p.Wd1)[q * 512 + t];
#pragma unroll
    for (int q = 0; q < 2; ++q) {
      int i4 = q * 512 + t;
      int s = i4 >> 4, c = (i4 & 15) * 4;
      *(float4*)&s_f[s * 64 + c] =
          *(const float4*)&p.cs[(size_t)(n * 64 + s) * DMODEL + c];
    }
    if (t < 64) {
      s_wd2[t] = p.Wd2[t];
      s_bd1[t] = p.bd1[t];
      p.pos[n * 64 + t] = t;
    }
    __syncthreads();
    for (int pr = wave; pr < 63; pr += 8) {
      float hs = s_bd1[lane];
#pragma unroll 8
      for (int kk = 0; kk < 64; ++kk) hs += s_f[pr * 64 + kk] * s_wd1[kk * 64 + lane];
#pragma unroll 8
      for (int kk = 0; kk < 64; ++kk) hs += s_f[(pr + 1) * 64 + kk] * s_wd1[(64 + kk) * 64 + lane];
      float g = wred_sum(gelu_f(hs) * s_wd2[lane]);
      if (lane == 0) p.logits[n * 64 + pr] = g + p.bd2[0];
    }
    __syncthreads();
    sel_phase(p, 0, sI, smem);
  }
  gsync(p.bar, &nsync);

  // ---------- main serial loop
  for (int i = 0; i < 63; ++i) {
    gemm_mfma(p.xhi, p.xlo, p.w1f, W1PLANE, p.bc1, KIN, 32, 2, true,
              p.hhi, p.hlo, nullptr, smem);
    gsync(p.bar, &nsync);
    gemm_mfma(p.hhi, p.hlo, p.w2f, W2PLANE, p.bc2, NOUT, 64, 4, false,
              nullptr, nullptr, p.ct, smem);
    gsync(p.bar, &nsync);
    if (b < NBATCH) {
      epi_phase(p, i, smem, sred);
      if (i < 62) {
        __syncthreads();
        sel_phase(p, i + 1, sI, smem);
      }
    }
    gsync(p.bar, &nsync);
  }
}

extern "C" void kernel_launch(void* const* d_in, const int* in_sizes, int n_in,
                              void* d_out, int out_size, void* d_ws, size_t ws_size,
                              hipStream_t stream) {
  Par p;
  p.input = (const float*)d_in[0];
  p.mask = (const float*)d_in[1];
  p.Wi = (const float*)d_in[2];
  p.bi = (const float*)d_in[3];
  p.gi = (const float*)d_in[4];
  p.bti = (const float*)d_in[5];
  p.Wd1 = (const float*)d_in[6];
  p.bd1 = (const float*)d_in[7];
  p.Wd2 = (const float*)d_in[8];
  p.bd2 = (const float*)d_in[9];
  p.Wc1 = (const float*)d_in[10];
  p.bc1 = (const float*)d_in[11];
  p.Wc2 = (const float*)d_in[12];
  p.bc2 = (const float*)d_in[13];
  p.gc = (const float*)d_in[14];
  p.btc = (const float*)d_in[15];
  p.out = (float*)d_out;

  char* ws = (char*)d_ws;
  size_t off = 0;
  auto take = [&](size_t bytes) -> char* {
    char* r = ws + off;
    off += (bytes + 255) & ~(size_t)255;
    return r;
  };
  p.bar = (unsigned int*)take(1024);
  p.pos = (int*)take(128 * 64 * 4);
  p.ksel = (int*)take(128 * 4);
  p.logits = (float*)take(128 * 64 * 4);
  p.ct = (float*)take((size_t)128 * 2048 * 4);
  p.cs = (float*)take((size_t)128 * 64 * 512 * 4);
  p.xhi = (unsigned short*)take((size_t)128 * 1024 * 2);
  p.xlo = (unsigned short*)take((size_t)128 * 1024 * 2);
  p.hhi = (unsigned short*)take((size_t)128 * 2048 * 2);
  p.hlo = (unsigned short*)take((size_t)128 * 2048 * 2);
  p.w1f = (unsigned short*)take((size_t)2 * W1PLANE * 2);
  p.w2f = (unsigned short*)take((size_t)2 * W2PLANE * 2);
  // total ~43.5 MB of d_ws

  hipLaunchKernelGGL(egt_zero, dim3(1), dim3(256), 0, stream, p.bar);
  void* args[] = {&p};
  hipError_t err = hipLaunchCooperativeKernel(egt_main, dim3(256), dim3(512), args, 0, stream);
  if (err != hipSuccess) {
    (void)hipGetLastError();  // manual barrier works under plain launch too
    hipLaunchKernelGGL(egt_main, dim3(256), dim3(512), 0, stream, p);
  }
}

// Round 9
// 2457.919 us; speedup vs baseline: 6.1220x; 2.1468x over previous
//
#include <hip/hip_runtime.h>

#define NBATCH 128
#define DMODEL 512
#define FDIM 64
#define KIN 1024
#define NOUT 2048

typedef __attribute__((ext_vector_type(8))) short bf16x8;
typedef __attribute__((ext_vector_type(4))) float f32x4;
typedef __attribute__((ext_vector_type(4))) unsigned int u32x4;
typedef __attribute__((ext_vector_type(2))) unsigned int u32x2;

struct Par {
  const float *input, *mask, *Wi, *bi, *gi, *bti;
  const float *Wd1, *bd1, *Wd2, *bd2;
  const float *Wc1, *bc1, *Wc2, *bc2, *gc, *btc;
  float *out;
  float *cs, *ct, *logits;
  unsigned short *xhi, *xlo, *hhi, *hlo, *w1f, *w2f;
  int *pos, *ksel;
  unsigned int *flags;
};

#define W1PLANE 2097152u   // 128*32*512 u16 per plane
#define W2PLANE 4194304u   // 128*64*512 u16 per plane

__device__ __forceinline__ float gelu_f(float v) {
  float u = 0.7978845608028654f * (v + 0.044715f * v * v * v);
  return 0.5f * v * (1.0f + tanhf(u));
}
__device__ __forceinline__ float sigm_f(float v) { return 1.0f / (1.0f + expf(-v)); }

__device__ __forceinline__ float wred_sum(float v) {
#pragma unroll
  for (int o = 32; o > 0; o >>= 1) v += __shfl_xor(v, o, 64);
  return v;
}

__device__ __forceinline__ unsigned short bf16rn(float v) {
  unsigned int u = __float_as_uint(v);
  return (unsigned short)((u + 0x7FFFu + ((u >> 16) & 1u)) >> 16);
}
__device__ __forceinline__ float bf16hi_f(unsigned short h) {
  return __uint_as_float(((unsigned int)h) << 16);
}

// ---- system-coherent (L1/L2-bypass) accessors: keep per-XCD L2 weight-resident.
// All asm operands are ext_vector_type / scalar (struct vec types unsupported).
__device__ __forceinline__ void ldx4_sys4(const void* p0, const void* p1,
                                          const void* p2, const void* p3,
                                          u32x4& a, u32x4& b, u32x4& c, u32x4& d) {
  asm volatile(
      "global_load_dwordx4 %0, %4, off sc0 sc1\n\t"
      "global_load_dwordx4 %1, %5, off sc0 sc1\n\t"
      "global_load_dwordx4 %2, %6, off sc0 sc1\n\t"
      "global_load_dwordx4 %3, %7, off sc0 sc1\n\t"
      "s_waitcnt vmcnt(0)"
      : "=&v"(a), "=&v"(b), "=&v"(c), "=&v"(d)
      : "v"(p0), "v"(p1), "v"(p2), "v"(p3)
      : "memory");
}
__device__ __forceinline__ void ld1_sys4(const void* p0, const void* p1,
                                         const void* p2, const void* p3,
                                         unsigned int& a, unsigned int& b,
                                         unsigned int& c, unsigned int& d) {
  asm volatile(
      "global_load_dword %0, %4, off sc0 sc1\n\t"
      "global_load_dword %1, %5, off sc0 sc1\n\t"
      "global_load_dword %2, %6, off sc0 sc1\n\t"
      "global_load_dword %3, %7, off sc0 sc1\n\t"
      "s_waitcnt vmcnt(0)"
      : "=&v"(a), "=&v"(b), "=&v"(c), "=&v"(d)
      : "v"(p0), "v"(p1), "v"(p2), "v"(p3)
      : "memory");
}
__device__ __forceinline__ unsigned int ld1_sys(const void* p) {
  unsigned int r;
  asm volatile("global_load_dword %0, %1, off sc0 sc1\n\ts_waitcnt vmcnt(0)"
               : "=&v"(r) : "v"(p) : "memory");
  return r;
}
__device__ __forceinline__ void st1_sys(void* p, unsigned int v) {
  asm volatile("global_store_dword %0, %1, off sc0 sc1" :: "v"(p), "v"(v) : "memory");
}
__device__ __forceinline__ void st2_sys(void* p, u32x2 v) {
  asm volatile("global_store_dwordx2 %0, %1, off sc0 sc1" :: "v"(p), "v"(v) : "memory");
}
__device__ __forceinline__ void st4_sys(void* p, u32x4 v) {
  asm volatile("global_store_dwordx4 %0, %1, off sc0 sc1" :: "v"(p), "v"(v) : "memory");
}
__device__ __forceinline__ void sth_sys(void* p, unsigned int v) {
  asm volatile("global_store_short %0, %1, off sc0 sc1" :: "v"(p), "v"(v) : "memory");
}

// ---- flag-array grid barrier: monotonic counters, bypass stores/loads,
// no atomics, no cache invalidation (weights stay in L2).
__device__ __forceinline__ void gsync(unsigned int* flags, unsigned int* tgt) {
  unsigned int target = ++(*tgt);
  asm volatile("s_waitcnt vmcnt(0) lgkmcnt(0)" ::: "memory");
  __syncthreads();  // all threads' bypass stores drained
  int t = threadIdx.x;
  if (t == 0) st1_sys(&flags[blockIdx.x], target);
  if (t < 256) {
    while (ld1_sys(&flags[t]) < target) __builtin_amdgcn_s_sleep(2);
  }
  __syncthreads();
}

// ---- SEL: argmax + pos/logit shift; emit x = [l,r] as bf16 hi/lo planes + LDS fp32 stash
__device__ void sel_phase(const Par& p, int i, int* sI, float* smem) {
  int n = blockIdx.x;
  int t = threadIdx.x, wave = t >> 6, lane = t & 63;
  int P = 63 - i;
  if (wave == 0) {
    float v = -3.0e38f;
    int idx = 1 << 20;
    if (lane < P) {
      v = p.logits[n * 64 + lane];
      float mk = p.mask[n * 64 + i + 1 + lane];
      if (!(mk > 0.0f)) v = -1.0e9f;
      idx = lane;
    }
#pragma unroll
    for (int o = 32; o > 0; o >>= 1) {
      float v2 = __shfl_xor(v, o, 64);
      int i2 = __shfl_xor(idx, o, 64);
      if (v2 > v || (v2 == v && i2 < idx)) { v = v2; idx = i2; }
    }
    if (lane == 0) {
      p.ksel[n] = idx;
      sI[0] = idx;
      sI[1] = p.pos[n * 64 + idx];
      sI[2] = p.pos[n * 64 + idx + 1];
    }
  }
  __syncthreads();
  int k = sI[0], slot_l = sI[1], slot_r = sI[2];
  if (wave == 1) {  // shift pos (wave-lockstep load-before-store)
    int j = lane;
    if (j >= k + 1 && j <= 62 - i) {
      int tmp = p.pos[n * 64 + j + 1];
      p.pos[n * 64 + j] = tmp;
    }
  } else if (wave == 2) {  // shift logits
    int j = lane;
    if (j >= k && j <= 61 - i) {
      float tmp = p.logits[n * 64 + j + 1];
      p.logits[n * 64 + j] = tmp;
    }
  }
  float* sx = smem + 12544;  // survives g1/g2 (they use floats [0,12544))
  if (t < 256) {
    const float* srcp = (t < 128) ? &p.cs[(size_t)(n * 64 + slot_l) * DMODEL]
                                  : &p.cs[(size_t)(n * 64 + slot_r) * DMODEL];
    int so = (t & 127) * 4;
    int o = (t < 128) ? so : (512 + so);
    float4 v = *(const float4*)&srcp[so];
    *(float4*)&sx[o] = v;
    ushort4 hi, lo;
    hi.x = bf16rn(v.x); lo.x = bf16rn(v.x - bf16hi_f(hi.x));
    hi.y = bf16rn(v.y); lo.y = bf16rn(v.y - bf16hi_f(hi.y));
    hi.z = bf16rn(v.z); lo.z = bf16rn(v.z - bf16hi_f(hi.z));
    hi.w = bf16rn(v.w); lo.w = bf16rn(v.w - bf16hi_f(hi.w));
    u32x2 uh, ul;
    uh.x = (unsigned)hi.x | ((unsigned)hi.y << 16);
    uh.y = (unsigned)hi.z | ((unsigned)hi.w << 16);
    ul.x = (unsigned)lo.x | ((unsigned)lo.y << 16);
    ul.y = (unsigned)lo.z | ((unsigned)lo.w << 16);
    st2_sys(&p.xhi[(size_t)n * KIN + o], uh);
    st2_sys(&p.xlo[(size_t)n * KIN + o], ul);
  }
}

// ---- split-bf16 MFMA GEMM (layout identical to round 7; A via bypass loads,
// B-frags via plain cached loads -> stay resident in XCD-pinned L2)
__device__ void gemm_mfma(const unsigned short* Ahi, const unsigned short* Alo,
                          const unsigned short* Bf, unsigned int bplane,
                          const float* bias, int K, int KS, int NCH, bool do_gelu,
                          unsigned short* Yhi, unsigned short* Ylo, float* Yf32,
                          float* smem) {
  int b = blockIdx.x, t = threadIdx.x;
  int m = (b >> 3) & 7;
  int ng = ((b >> 6) << 3) | (b & 7);
  int rbase = m * 16;
  int w = t >> 6, lane = t & 63;
  int tile = w & 3, hv = w >> 2;
  int quad = lane >> 4, mr = lane & 15;
  int nt = ng * 4 + tile;
  int cbase = nt * 16;
  unsigned short* As = (unsigned short*)smem;  // [pl][hv][16][264] u16
  float* red = smem + 8448;                    // 4096 floats
  int KH = K >> 1;
  f32x4 acc = {0.f, 0.f, 0.f, 0.f};
  const unsigned short* bp0 = Bf + (size_t)nt * KS * 512 + lane * 8;
  const unsigned short* bp1 = bp0 + bplane;
  for (int ch = 0; ch < NCH; ++ch) {
    __syncthreads();
    const void* ap[4];
    int lo_[4];
#pragma unroll
    for (int q = 0; q < 4; ++q) {  // stage A: 2 planes x 2 k-halves x 16 rows x 256
      int g = q * 512 + t;
      int pl = g >> 10, hh = (g >> 9) & 1, r = (g >> 5) & 15, kg = g & 31;
      ap[q] = (pl ? Alo : Ahi) + (size_t)(rbase + r) * K + hh * KH + ch * 256 + kg * 8;
      lo_[q] = ((pl * 2 + hh) * 16 + r) * 264 + kg * 8;
    }
    u32x4 v0, v1, v2, v3;
    ldx4_sys4(ap[0], ap[1], ap[2], ap[3], v0, v1, v2, v3);
    *(u32x4*)&As[lo_[0]] = v0;
    *(u32x4*)&As[lo_[1]] = v1;
    *(u32x4*)&As[lo_[2]] = v2;
    *(u32x4*)&As[lo_[3]] = v3;
    __syncthreads();
    int ks0 = hv * (KS >> 1) + ch * 8;
    const unsigned short* a0 = &As[(hv * 16 + mr) * 264 + quad * 8];
    const unsigned short* a1 = &As[((2 + hv) * 16 + mr) * 264 + quad * 8];
#pragma unroll
    for (int s = 0; s < 8; ++s) {
      bf16x8 ah = *(const bf16x8*)(a0 + s * 32);
      bf16x8 al = *(const bf16x8*)(a1 + s * 32);
      bf16x8 bh = *(const bf16x8*)(bp0 + (size_t)(ks0 + s) * 512);
      bf16x8 bl = *(const bf16x8*)(bp1 + (size_t)(ks0 + s) * 512);
      acc = __builtin_amdgcn_mfma_f32_16x16x32_bf16(ah, bh, acc, 0, 0, 0);
      acc = __builtin_amdgcn_mfma_f32_16x16x32_bf16(ah, bl, acc, 0, 0, 0);
      acc = __builtin_amdgcn_mfma_f32_16x16x32_bf16(al, bh, acc, 0, 0, 0);
    }
  }
  if (hv == 1) *(f32x4*)&red[(tile * 64 + lane) * 4] = acc;
  __syncthreads();
  if (hv == 0) {
    f32x4 o4 = *(const f32x4*)&red[(tile * 64 + lane) * 4];
    float bb = bias[cbase + mr];
#pragma unroll
    for (int r = 0; r < 4; ++r) {
      float o = acc[r] + o4[r] + bb;
      int row = rbase + quad * 4 + r;  // C/D: col=lane&15, row=quad*4+reg
      if (do_gelu) {
        o = gelu_f(o);
        unsigned short h = bf16rn(o);
        unsigned short l = bf16rn(o - bf16hi_f(h));
        sth_sys(&Yhi[(size_t)row * NOUT + cbase + mr], (unsigned int)h);
        sth_sys(&Ylo[(size_t)row * NOUT + cbase + mr], (unsigned int)l);
      } else {
        st1_sys(&Yf32[(size_t)row * NOUT + cbase + mr], __float_as_uint(o));
      }
    }
  }
}

// ---- EPI: gates/blend/LN -> cs[slot_new]; recompute logits for pairs k-1, k
__device__ void epi_phase(const Par& p, int i, float* smem, float* sred) {
  int n = blockIdx.x;
  int t = threadIdx.x, wave = t >> 6, lane = t & 63;
  int Pn = 62 - i;
  int k = p.ksel[n];
  int slot_new = p.pos[n * 64 + k];
  float* s_wd1 = smem;          // [0, 8192)
  float* s_wd2 = smem + 8192;   // 64
  float* s_bd1 = smem + 8256;   // 64
  float* s_fnew = smem + 8320;  // 64
  float* sx = smem + 12544;     // x-row stash from sel
  if (i < 62) {
#pragma unroll
    for (int q = 0; q < 4; ++q)
      ((float4*)s_wd1)[q * 512 + t] = ((const float4*)p.Wd1)[q * 512 + t];
    if (t < 64) { s_wd2[t] = p.Wd2[t]; s_bd1[t] = p.bd1[t]; }
  }
  const float* ct = p.ct + (size_t)n * NOUT;
  int d = t;
  float lv = sx[d];
  float rv = sx[512 + d];
  unsigned int u0, u1, u2, u3;
  ld1_sys4(&ct[d], &ct[DMODEL + d], &ct[2 * DMODEL + d], &ct[3 * DMODEL + d],
           u0, u1, u2, u3);
  float c0 = __uint_as_float(u0), c1 = __uint_as_float(u1);
  float c2 = __uint_as_float(u2), c3 = __uint_as_float(u3);
  float s = sigm_f(c0) * lv + sigm_f(c1) * rv + sigm_f(c2) * c3;
  float part = wred_sum(s);
  if (lane == 0) sred[wave] = part;
  __syncthreads();
  float mm = 0.f;
#pragma unroll
  for (int ww = 0; ww < 8; ++ww) mm += sred[ww];
  mm *= (1.0f / 512.0f);
  float e = s - mm;
  float pq = wred_sum(e * e);
  if (lane == 0) sred[8 + wave] = pq;
  __syncthreads();
  float var = 0.f;
#pragma unroll
  for (int ww = 0; ww < 8; ++ww) var += sred[8 + ww];
  var *= (1.0f / 512.0f);
  float inv = 1.0f / sqrtf(var + 1e-5f);
  float nv = e * inv * p.gc[d] + p.btc[d];
  p.cs[(size_t)(n * 64 + slot_new) * DMODEL + d] = nv;  // block-local, cached
  if (i == 62) p.out[(size_t)n * DMODEL + d] = nv;
  if (d < FDIM) s_fnew[d] = nv;
  __syncthreads();
  if (i < 62) {
    if (wave == 0 && k >= 1) {
      const float* A = &p.cs[(size_t)(n * 64 + p.pos[n * 64 + (k - 1)]) * DMODEL];
      float hs = s_bd1[lane];
#pragma unroll 8
      for (int kk = 0; kk < 64; ++kk) hs += A[kk] * s_wd1[kk * 64 + lane];
#pragma unroll 8
      for (int kk = 0; kk < 64; ++kk) hs += s_fnew[kk] * s_wd1[(64 + kk) * 64 + lane];
      float g = wred_sum(gelu_f(hs) * s_wd2[lane]);
      if (lane == 0) p.logits[n * 64 + (k - 1)] = g + p.bd2[0];
    } else if (wave == 1 && k < Pn) {
      const float* Bv = &p.cs[(size_t)(n * 64 + p.pos[n * 64 + (k + 1)]) * DMODEL];
      float hs = s_bd1[lane];
#pragma unroll 8
      for (int kk = 0; kk < 64; ++kk) hs += s_fnew[kk] * s_wd1[kk * 64 + lane];
#pragma unroll 8
      for (int kk = 0; kk < 64; ++kk) hs += Bv[kk] * s_wd1[(64 + kk) * 64 + lane];
      float g = wred_sum(gelu_f(hs) * s_wd2[lane]);
      if (lane == 0) p.logits[n * 64 + k] = g + p.bd2[0];
    }
  }
}

__global__ void egt_zero(unsigned int* flags) { flags[threadIdx.x] = 0u; }

__global__ void __launch_bounds__(512, 2) egt_main(Par p) {
  __shared__ __align__(16) float smem[15872];  // 62 KB
  __shared__ float sred[16];
  __shared__ int sI[8];
  unsigned int nsync = 0;
  int b = blockIdx.x, t = threadIdx.x;
  int wave = t >> 6, lane = t & 63;

  // ---------- INIT-WTRANSFORM: Wc1/Wc2 fp32 -> B-frag-major bf16 hi/lo planes
  // (bypass stores -> LLC so all XCDs see them after the flag barrier)
  {
    int tid = b * 512 + t;
    for (int it = tid; it < 786432; it += 131072) {
      const float* W;
      unsigned short *dh, *dl;
      int nt, ks, l, KS2;
      if (it < 262144) {
        W = p.Wc1; dh = p.w1f; dl = p.w1f + W1PLANE;
        nt = it >> 11; int r2 = it & 2047; ks = r2 >> 6; l = r2 & 63; KS2 = 32;
      } else {
        int rem = it - 262144;
        W = p.Wc2; dh = p.w2f; dl = p.w2f + W2PLANE;
        nt = rem >> 12; int r2 = rem & 4095; ks = r2 >> 6; l = r2 & 63; KS2 = 64;
      }
      int k0 = ks * 32 + (l >> 4) * 8;
      int n = nt * 16 + (l & 15);
      unsigned int hw[4], lw[4];
#pragma unroll
      for (int jj = 0; jj < 4; ++jj) {
        float v0 = W[(size_t)(k0 + 2 * jj) * NOUT + n];
        float v1 = W[(size_t)(k0 + 2 * jj + 1) * NOUT + n];
        unsigned short h0 = bf16rn(v0), h1 = bf16rn(v1);
        unsigned short l0 = bf16rn(v0 - bf16hi_f(h0));
        unsigned short l1 = bf16rn(v1 - bf16hi_f(h1));
        hw[jj] = (unsigned int)h0 | ((unsigned int)h1 << 16);
        lw[jj] = (unsigned int)l0 | ((unsigned int)l1 << 16);
      }
      size_t o = ((size_t)nt * KS2 + ks) * 512 + l * 8;
      u32x4 H; H.x = hw[0]; H.y = hw[1]; H.z = hw[2]; H.w = hw[3];
      u32x4 L; L.x = lw[0]; L.y = lw[1]; L.z = lw[2]; L.w = lw[3];
      st4_sys(&dh[o], H);
      st4_sys(&dl[o], L);
    }
  }

  // ---------- INIT-PROJ: cs0 = LN(input @ Wi + bi); 32 (n,s)-rows per block
  // (cs written via bypass stores; read later by a different block)
  {
    int rbase = b * 32;
    int n_ = b >> 1;
    float acc[32];
#pragma unroll
    for (int r = 0; r < 32; ++r) acc[r] = 0.f;
    float* xs = smem;  // [32][64]
    const float* Wi = p.Wi;
    for (int kc = 0; kc < 512; kc += 64) {
      __syncthreads();
      {
        int flat = t * 4;
        int r = flat >> 6, c = flat & 63;
        *(float4*)&xs[flat] =
            *(const float4*)&p.input[(size_t)(rbase + r) * 512 + kc + c];
      }
      __syncthreads();
      for (int k = 0; k < 64; k += 4) {
        float w0 = Wi[(size_t)(kc + k + 0) * 512 + t];
        float w1 = Wi[(size_t)(kc + k + 1) * 512 + t];
        float w2 = Wi[(size_t)(kc + k + 2) * 512 + t];
        float w3 = Wi[(size_t)(kc + k + 3) * 512 + t];
#pragma unroll
        for (int r = 0; r < 32; ++r) {
          float4 xv = *(const float4*)&xs[r * 64 + k];
          acc[r] += xv.x * w0 + xv.y * w1 + xv.z * w2 + xv.w * w3;
        }
      }
    }
    float* row8 = smem;  // [8][512]
#pragma unroll
    for (int chunk = 0; chunk < 4; ++chunk) {
      __syncthreads();
#pragma unroll
      for (int rr = 0; rr < 8; ++rr)
        row8[rr * 512 + t] = acc[chunk * 8 + rr] + p.bi[t];
      __syncthreads();
      int rr = wave;
      float vals[8];
      float sum = 0.f;
#pragma unroll
      for (int jj = 0; jj < 8; ++jj) {
        float v = row8[rr * 512 + jj * 64 + lane];
        vals[jj] = v;
        sum += v;
      }
      sum = wred_sum(sum);
      float mm = sum * (1.0f / 512.0f);
      float sq = 0.f;
#pragma unroll
      for (int jj = 0; jj < 8; ++jj) { float dd = vals[jj] - mm; sq += dd * dd; }
      sq = wred_sum(sq);
      float inv = 1.0f / sqrtf(sq * (1.0f / 512.0f) + 1e-5f);
      int r = chunk * 8 + rr;
      int ss = (b & 1) * 32 + r;
      float* dst = &p.cs[(size_t)(n_ * 64 + ss) * DMODEL];
#pragma unroll
      for (int jj = 0; jj < 8; ++jj) {
        int c = jj * 64 + lane;
        st1_sys(&dst[c], __float_as_uint((vals[jj] - mm) * inv * p.gi[c] + p.bti[c]));
      }
    }
  }
  gsync(p.flags, &nsync);

  // ---------- INIT-SCORE: 63 pair logits per row; init pos; SEL(0)
  if (b < NBATCH) {
    int n = b;
    float* s_wd1 = smem;          // 8192 floats
    float* s_f = smem + 8192;     // 4096 floats
    float* s_wd2 = smem + 12288;  // 64
    float* s_bd1 = smem + 12352;  // 64
#pragma unroll
    for (int q = 0; q < 4; ++q)
      ((float4*)s_wd1)[q * 512 + t] = ((const float4*)p.Wd1)[q * 512 + t];
#pragma unroll
    for (int q = 0; q < 2; ++q) {
      int i4 = q * 512 + t;
      int s = i4 >> 4, c = (i4 & 15) * 4;
      *(float4*)&s_f[s * 64 + c] =
          *(const float4*)&p.cs[(size_t)(n * 64 + s) * DMODEL + c];
    }
    if (t < 64) {
      s_wd2[t] = p.Wd2[t];
      s_bd1[t] = p.bd1[t];
      p.pos[n * 64 + t] = t;
    }
    __syncthreads();
    for (int pr = wave; pr < 63; pr += 8) {
      float hs = s_bd1[lane];
#pragma unroll 8
      for (int kk = 0; kk < 64; ++kk) hs += s_f[pr * 64 + kk] * s_wd1[kk * 64 + lane];
#pragma unroll 8
      for (int kk = 0; kk < 64; ++kk) hs += s_f[(pr + 1) * 64 + kk] * s_wd1[(64 + kk) * 64 + lane];
      float g = wred_sum(gelu_f(hs) * s_wd2[lane]);
      if (lane == 0) p.logits[n * 64 + pr] = g + p.bd2[0];
    }
    __syncthreads();
    sel_phase(p, 0, sI, smem);
  }
  gsync(p.flags, &nsync);

  // ---------- main serial loop
  for (int i = 0; i < 63; ++i) {
    gemm_mfma(p.xhi, p.xlo, p.w1f, W1PLANE, p.bc1, KIN, 32, 2, true,
              p.hhi, p.hlo, nullptr, smem);
    gsync(p.flags, &nsync);
    gemm_mfma(p.hhi, p.hlo, p.w2f, W2PLANE, p.bc2, NOUT, 64, 4, false,
              nullptr, nullptr, p.ct, smem);
    gsync(p.flags, &nsync);
    if (b < NBATCH) {
      epi_phase(p, i, smem, sred);
      if (i < 62) {
        __syncthreads();
        sel_phase(p, i + 1, sI, smem);
      }
    }
    gsync(p.flags, &nsync);
  }
}

extern "C" void kernel_launch(void* const* d_in, const int* in_sizes, int n_in,
                              void* d_out, int out_size, void* d_ws, size_t ws_size,
                              hipStream_t stream) {
  Par p;
  p.input = (const float*)d_in[0];
  p.mask = (const float*)d_in[1];
  p.Wi = (const float*)d_in[2];
  p.bi = (const float*)d_in[3];
  p.gi = (const float*)d_in[4];
  p.bti = (const float*)d_in[5];
  p.Wd1 = (const float*)d_in[6];
  p.bd1 = (const float*)d_in[7];
  p.Wd2 = (const float*)d_in[8];
  p.bd2 = (const float*)d_in[9];
  p.Wc1 = (const float*)d_in[10];
  p.bc1 = (const float*)d_in[11];
  p.Wc2 = (const float*)d_in[12];
  p.bc2 = (const float*)d_in[13];
  p.gc = (const float*)d_in[14];
  p.btc = (const float*)d_in[15];
  p.out = (float*)d_out;

  char* ws = (char*)d_ws;
  size_t off = 0;
  auto take = [&](size_t bytes) -> char* {
    char* r = ws + off;
    off += (bytes + 255) & ~(size_t)255;
    return r;
  };
  p.flags = (unsigned int*)take(1024);
  p.pos = (int*)take(128 * 64 * 4);
  p.ksel = (int*)take(128 * 4);
  p.logits = (float*)take(128 * 64 * 4);
  p.ct = (float*)take((size_t)128 * 2048 * 4);
  p.cs = (float*)take((size_t)128 * 64 * 512 * 4);
  p.xhi = (unsigned short*)take((size_t)128 * 1024 * 2);
  p.xlo = (unsigned short*)take((size_t)128 * 1024 * 2);
  p.hhi = (unsigned short*)take((size_t)128 * 2048 * 2);
  p.hlo = (unsigned short*)take((size_t)128 * 2048 * 2);
  p.w1f = (unsigned short*)take((size_t)2 * W1PLANE * 2);
  p.w2f = (unsigned short*)take((size_t)2 * W2PLANE * 2);
  // total ~43.5 MB of d_ws

  hipLaunchKernelGGL(egt_zero, dim3(1), dim3(256), 0, stream, p.flags);
  void* args[] = {&p};
  hipError_t err = hipLaunchCooperativeKernel(egt_main, dim3(256), dim3(512), args, 0, stream);
  if (err != hipSuccess) {
    (void)hipGetLastError();  // manual barrier works under plain launch too
    hipLaunchKernelGGL(egt_main, dim3(256), dim3(512), 0, stream, p);
  }
}